// Round 10
// baseline (393.369 us; speedup 1.0000x reference)
//
#include <hip/hip_runtime.h>
#include <math.h>

// ASG loss, MI355X. inputs (T,B,L) f32, trans (L,L) f32, targets (B,S) i32,
// input_lengths (B,) i32, target_lengths (B,) i32. out = mean(full - aligned).
//
// asg_k1 (1152 blocks x 256):
//   blocks 0..63    : fac FORWARD chain, t = 1..TS (exp domain, f64 states)
//   blocks 64..127  : fac BACKWARD chain, t = len-1..TS+1 (transposed recur.)
//   blocks 128..1151: fcc phase 1, BARRIER-FREE: each WAVE owns one 64-step
//     segment product P = prod diag(e_t)·W. Constant bf16 W A-frags;
//     16 MFMA/step (4 quadrants x K=64); e applied on the D side; P in
//     wave-private LDS (dbuf). Waves 2,3 exit. No __syncthreads in this path.
// asg_k2 (64 blocks): per-batch scan over 32 segment matrices + LSE.
// asg_k3 (1 block): per-batch dot(fwd,bwd) in f64 + log + mean combine.
// NOTE: needs ~17.1 MB of d_ws.

constexpr int T_ = 2048, B_ = 64, L_ = 64, S_ = 256;
constexpr int CSEG = 64, NSEG = 32;  // fcc segments cover t = 1..2047
constexpr int FCH = 16;              // fac chunk rows
constexpr float LN2 = 0.6931471805599453f;

typedef __bf16 bf16x8 __attribute__((ext_vector_type(8)));
typedef __bf16 bf16x4 __attribute__((ext_vector_type(4)));
typedef float f32x16 __attribute__((ext_vector_type(16)));

constexpr size_t OFF_SCALE = (size_t)NSEG * B_ * 4096 * 2;  // 16 MB M_seg
constexpr size_t OFF_FULL = OFF_SCALE + (size_t)NSEG * B_ * 4;
constexpr size_t OFF_FWD = OFF_FULL + B_ * 4;
constexpr size_t OFF_BWD = OFF_FWD + (size_t)B_ * 256 * 8;
constexpr size_t OFF_LF = OFF_BWD + (size_t)B_ * 256 * 8;
constexpr size_t OFF_LB = OFF_LF + B_ * 4;

__device__ __forceinline__ float wave_max64(float v) {
#pragma unroll
  for (int off = 1; off < 64; off <<= 1) v = fmaxf(v, __shfl_xor(v, off, 64));
  return v;
}
__device__ __forceinline__ float wave_sum64(float v) {
#pragma unroll
  for (int off = 1; off < 64; off <<= 1) v += __shfl_xor(v, off, 64);
  return v;
}
__device__ __forceinline__ double wave_max64d(double v) {
#pragma unroll
  for (int off = 1; off < 64; off <<= 1) v = fmax(v, __shfl_xor(v, off, 64));
  return v;
}

struct P1W {  // one segment-wave's private storage (26.88 KB)
  __align__(16) __bf16 P[2][64 * 68];  // col-major [n][k], stride 68
  __align__(16) __bf16 xs[64][72];     // exp(x_t - m_t), bf16, pad 8
  __align__(16) float m[64];           // row maxes
};
struct P1shm {
  P1W w[2];
};
struct FACshm {
  __align__(16) float E[2][FCH][64];    // exp(x - m_row), 8 KB
  __align__(16) float Eg[2][FCH][256];  // gathered, compute layout, 32 KB
  __align__(16) float m_fac[2][FCH];    // row maxes (stage-side)
  __align__(16) float mg[2][FCH];       // row maxes (compute-side copy)
};
union KU {
  P1shm p1;
  FACshm fac;
};

__global__ __launch_bounds__(256) void asg_k1(
    const float* __restrict__ inputs, const float* __restrict__ trans,
    const int* __restrict__ targets, const int* __restrict__ ilen,
    const int* __restrict__ tlenp, char* __restrict__ ws) {
  __shared__ KU u;
  const int tid = threadIdx.x, lane = tid & 63, wv = tid >> 6;
  const int bid = blockIdx.x;
  float* scales = (float*)(ws + OFF_SCALE);

  if (bid < 2 * B_) {
    // ================== FAC half-chains (exp domain, f64) ==================
    const bool isfwd = (bid < B_);
    const int b = bid & 63;
    const int len = ilen[b];
    const int tl = tlenp[b];
    const int TS = (len - 1) >> 1;
    double* vecout = (double*)(ws + (isfwd ? OFF_FWD : OFF_BWD)) + b * 256;
    float* Lout = (float*)(ws + (isfwd ? OFF_LF : OFF_LB));

    int tg0 = 0, tg1 = 0, tg2 = 0, tg3 = 0;
    if (wv == 0 || wv == 2) {
      int4 t4 = *(const int4*)(targets + b * S_ + lane * 4);
      tg0 = t4.x; tg1 = t4.y; tg2 = t4.z; tg3 = t4.w;
    }
    auto stage = [&](int c, int buf) {  // wave1
#pragma unroll
      for (int i = 0; i < 4; ++i) {
        int f = lane + 64 * i;
        int r = f >> 4, c4 = f & 15;
        int t = c * FCH + r;
        if (t > T_ - 1) t = T_ - 1;
        float4 v = *(const float4*)(inputs + (size_t)t * (B_ * L_) + b * L_ +
                                    c4 * 4);
        float m = fmaxf(fmaxf(v.x, v.y), fmaxf(v.z, v.w));
#pragma unroll
        for (int off = 1; off < 16; off <<= 1)
          m = fmaxf(m, __shfl_xor(m, off, 64));
        v.x = __expf(v.x - m); v.y = __expf(v.y - m);
        v.z = __expf(v.z - m); v.w = __expf(v.w - m);
        *(float4*)&u.fac.E[buf][r][c4 * 4] = v;
        if ((lane & 15) == 0) u.fac.m_fac[buf][r] = m;
      }
    };
    auto regather = [&](int c, int buf) {  // wave2
#pragma unroll 4
      for (int r = 0; r < FCH; ++r) {
        float4 h;
        h.x = u.fac.E[buf][r][tg0]; h.y = u.fac.E[buf][r][tg1];
        h.z = u.fac.E[buf][r][tg2]; h.w = u.fac.E[buf][r][tg3];
        *(float4*)&u.fac.Eg[buf][r][lane * 4] = h;
      }
      if (lane < FCH) u.fac.mg[buf][lane] = u.fac.m_fac[buf][lane];
    };

    if (isfwd) {
      // ---------------- FORWARD: t = 1..TS ----------------
      double sw0 = 0, sw1 = 0, sw2 = 0, sw3 = 0;
      double mw0 = 0, mw1 = 0, mw2 = 0, mw3 = 0;
      if (wv == 0) {
        int tgm1 = (lane > 0) ? targets[b * S_ + lane * 4 - 1] : 0;
        sw0 = exp((double)trans[tg0 * 64 + tg0]);
        sw1 = exp((double)trans[tg1 * 64 + tg1]);
        sw2 = exp((double)trans[tg2 * 64 + tg2]);
        sw3 = exp((double)trans[tg3 * 64 + tg3]);
        mw0 = (lane == 0) ? 0.0 : exp((double)trans[tg0 * 64 + tgm1]);
        mw1 = exp((double)trans[tg1 * 64 + tg0]);
        mw2 = exp((double)trans[tg2 * 64 + tg1]);
        mw3 = exp((double)trans[tg3 * 64 + tg2]);
      }
      if (wv == 1) { stage(0, 0); stage(1, 1); }
      __syncthreads();
      if (wv == 2) regather(0, 0);
      __syncthreads();

      double d0 = 0.0, d1 = 0.0, d2 = 0.0, d3 = 0.0, shv = 0.0;
      float Lacc = 0.0f;
      const int addr_up = ((lane + 63) & 63) << 2;
      if (wv == 0) {
        if (lane == 0) d0 = (double)u.fac.Eg[0][0][0];
        Lacc = u.fac.mg[0][0];
        __builtin_amdgcn_s_setprio(1);
      }
      for (int c = 0; 16 * c <= TS; ++c) {
        const int buf = c & 1;
        if (wv == 1) {
          if (16 * (c + 2) <= TS) stage(c + 2, buf);
        } else if (wv == 2) {
          if (16 * (c + 1) <= TS) regather(c + 1, buf ^ 1);
        } else if (wv == 0) {
          if (c) {  // exact power-of-2 rescale
            double dmax = wave_max64d(fmax(fmax(d0, d1), fmax(d2, d3)));
            long long lm = __double_as_longlong(dmax);
            int ex = (int)((lm >> 52) & 0x7FF);
            double M = __longlong_as_double((long long)(2046 - ex) << 52);
            d0 *= M; d1 *= M; d2 *= M; d3 *= M; shv *= M;
            Lacc += (float)(ex - 1023) * LN2;
          }
          const int r0 = (c == 0) ? 1 : 0;
          const int rmax = min(FCH, TS + 1 - 16 * c);
          float4 eH = *(const float4*)&u.fac.Eg[buf][r0][lane * 4];
          float mH = u.fac.mg[buf][r0];
          const int r1 = min(r0 + 1, FCH - 1);
          float4 pH = *(const float4*)&u.fac.Eg[buf][r1][lane * 4];
          float pM = u.fac.mg[buf][r1];
          for (int r = r0; r < rmax; ++r) {
            const int rn = min(r + 2, FCH - 1);
            float4 nH = *(const float4*)&u.fac.Eg[buf][rn][lane * 4];
            float nM = u.fac.mg[buf][rn];
            double nd3 = (double)eH.w * fma(mw3, d2, sw3 * d3);
            long long l3 = __double_as_longlong(nd3);
            int slo = __builtin_amdgcn_ds_bpermute(addr_up, (int)l3);
            int shi = __builtin_amdgcn_ds_bpermute(addr_up, (int)(l3 >> 32));
            double nd0 = (double)eH.x * fma(mw0, shv, sw0 * d0);
            double nd1 = (double)eH.y * fma(mw1, d0, sw1 * d1);
            double nd2 = (double)eH.z * fma(mw2, d1, sw2 * d2);
            d0 = nd0; d1 = nd1; d2 = nd2; d3 = nd3;
            shv = __longlong_as_double(((long long)shi << 32) |
                                       (unsigned int)slo);
            Lacc += mH;
            eH = pH; mH = pM; pH = nH; pM = nM;
          }
        }
        __syncthreads();
      }
      if (wv == 0) {
        __builtin_amdgcn_s_setprio(0);
        vecout[lane * 4 + 0] = d0; vecout[lane * 4 + 1] = d1;
        vecout[lane * 4 + 2] = d2; vecout[lane * 4 + 3] = d3;
        if (lane == 0) Lout[b] = Lacc;
      }
    } else {
      // ---------------- BACKWARD: t = len-1..TS+1 (transposed) ----------
      double sw0 = 0, sw1 = 0, sw2 = 0, sw3 = 0;
      double mv0 = 0, mv1 = 0, mv2 = 0, mv3 = 0;
      if (wv == 0) {
        int tg4 = (lane < 63) ? targets[b * S_ + lane * 4 + 4] : 0;
        sw0 = exp((double)trans[tg0 * 64 + tg0]);
        sw1 = exp((double)trans[tg1 * 64 + tg1]);
        sw2 = exp((double)trans[tg2 * 64 + tg2]);
        sw3 = exp((double)trans[tg3 * 64 + tg3]);
        mv0 = exp((double)trans[tg1 * 64 + tg0]);
        mv1 = exp((double)trans[tg2 * 64 + tg1]);
        mv2 = exp((double)trans[tg3 * 64 + tg2]);
        mv3 = (lane < 63) ? exp((double)trans[tg4 * 64 + tg3]) : 0.0;
      }
      const int cmax = (len - 1) >> 4;
      const int cmin = (TS + 1) >> 4;
      if (wv == 1) {
        stage(cmax, cmax & 1);
        if (cmax - 1 >= cmin) stage(cmax - 1, (cmax - 1) & 1);
      }
      __syncthreads();
      if (wv == 2) regather(cmax, cmax & 1);
      __syncthreads();

      const int idx = tl - 1;
      double b0 = 0, b1 = 0, b2 = 0, b3 = 0, g0cur = 0, shg = 0;
      float Lacc = 0.0f;
      const int addr_dn = ((lane + 1) & 63) << 2;
      if (wv == 0) {
        b0 = (lane * 4 + 0 == idx) ? 1.0 : 0.0;
        b1 = (lane * 4 + 1 == idx) ? 1.0 : 0.0;
        b2 = (lane * 4 + 2 == idx) ? 1.0 : 0.0;
        b3 = (lane * 4 + 3 == idx) ? 1.0 : 0.0;
        const int rh0 = (len - 1) & 15;
        float e0x = u.fac.Eg[cmax & 1][rh0][lane * 4];
        g0cur = (double)e0x * b0;
        long long lg = __double_as_longlong(g0cur);
        int slo = __builtin_amdgcn_ds_bpermute(addr_dn, (int)lg);
        int shi = __builtin_amdgcn_ds_bpermute(addr_dn, (int)(lg >> 32));
        shg = __longlong_as_double(((long long)shi << 32) | (unsigned int)slo);
        __builtin_amdgcn_s_setprio(1);
      }
      for (int c = cmax; c >= cmin; --c) {
        const int buf = c & 1;
        if (wv == 1) {
          if (c - 2 >= cmin) stage(c - 2, buf);
        } else if (wv == 2) {
          if (c - 1 >= cmin) regather(c - 1, buf ^ 1);
        } else if (wv == 0) {
          if (c != cmax) {
            double dmax = wave_max64d(fmax(fmax(b0, b1), fmax(b2, b3)));
            long long lm = __double_as_longlong(dmax);
            int ex = (int)((lm >> 52) & 0x7FF);
            double M = __longlong_as_double((long long)(2046 - ex) << 52);
            b0 *= M; b1 *= M; b2 *= M; b3 *= M; g0cur *= M; shg *= M;
            Lacc += (float)(ex - 1023) * LN2;
          }
          const int rhi = (c == cmax) ? ((len - 1) & 15) : FCH - 1;
          const int rlo = max(0, (TS + 1) - 16 * c);
          float4 eH = *(const float4*)&u.fac.Eg[buf][rhi][lane * 4];
          float mH = u.fac.mg[buf][rhi];
          const int r1 = max(rhi - 1, rlo);
          float4 pH = *(const float4*)&u.fac.Eg[buf][r1][lane * 4];
          float pM = u.fac.mg[buf][r1];
          for (int r = rhi; r >= rlo; --r) {
            const int rn = max(r - 2, rlo);
            float4 nH = *(const float4*)&u.fac.Eg[buf][rn][lane * 4];
            float nM = u.fac.mg[buf][rn];
            double g1 = (double)eH.y * b1;
            double g2 = (double)eH.z * b2;
            double g3 = (double)eH.w * b3;
            double nb0 = fma(mv0, g1, sw0 * g0cur);
            double nb1 = fma(mv1, g2, sw1 * g1);
            double nb2 = fma(mv2, g3, sw2 * g2);
            double nb3 = fma(mv3, shg, sw3 * g3);
            double g0n = (double)pH.x * nb0;
            long long lg2 = __double_as_longlong(g0n);
            int slo2 = __builtin_amdgcn_ds_bpermute(addr_dn, (int)lg2);
            int shi2 = __builtin_amdgcn_ds_bpermute(addr_dn, (int)(lg2 >> 32));
            b0 = nb0; b1 = nb1; b2 = nb2; b3 = nb3;
            g0cur = g0n;
            shg = __longlong_as_double(((long long)shi2 << 32) |
                                       (unsigned int)slo2);
            Lacc += mH;
            eH = pH; mH = pM; pH = nH; pM = nM;
          }
        }
        __syncthreads();
      }
      if (wv == 0) {
        __builtin_amdgcn_s_setprio(0);
        vecout[lane * 4 + 0] = b0; vecout[lane * 4 + 1] = b1;
        vecout[lane * 4 + 2] = b2; vecout[lane * 4 + 3] = b3;
        if (lane == 0) Lout[b] = Lacc;
      }
    }
    return;
  }

  // ============= FCC PHASE 1 (barrier-free, one segment per wave) =========
  if (wv >= 2) return;  // waves 2,3 unused in this path
  const int sid = (bid - 2 * B_) * 2 + wv;  // 0..2047
  const int b = sid >> 5, s = sid & 31;
  const int t0 = 1 + s * CSEG;
  const int len = ilen[b];
  P1W& W = u.p1.w[wv];
  const int hh = lane >> 5;
  int ke = min(CSEG, T_ - t0);
  ke = min(ke, len - t0);
  if (ke < 0) ke = 0;

  // stage xs = bf16(exp(x - rowmax)), rowmax in W.m
#pragma unroll
  for (int i = 0; i < 16; ++i) {
    int f = lane + 64 * i;
    int r = f >> 4, c4 = f & 15;
    int t = t0 + r;
    if (t > T_ - 1) t = T_ - 1;
    float4 v = *(const float4*)(inputs + (size_t)t * (B_ * L_) + b * L_ + c4 * 4);
    float m = fmaxf(fmaxf(v.x, v.y), fmaxf(v.z, v.w));
#pragma unroll
    for (int off = 1; off < 16; off <<= 1)
      m = fmaxf(m, __shfl_xor(m, off, 64));
    bf16x4 h;
    h[0] = (__bf16)__expf(v.x - m); h[1] = (__bf16)__expf(v.y - m);
    h[2] = (__bf16)__expf(v.z - m); h[3] = (__bf16)__expf(v.w - m);
    *(bf16x4*)&W.xs[r][c4 * 4] = h;
    if ((lane & 15) == 0) W.m[r] = m;
  }
  // P[0] = I
  for (int i = lane; i < 64 * 68; i += 64) W.P[0][i] = (__bf16)0.0f;
  W.P[0][lane * 68 + lane] = (__bf16)1.0f;

  // constant W A-frags (bf16): Wb[ma][kc]
  bf16x8 Wb[2][4];
#pragma unroll
  for (int ma = 0; ma < 2; ++ma) {
#pragma unroll
    for (int kc = 0; kc < 4; ++kc) {
      const float* tp = trans + (32 * ma + (lane & 31)) * 64 + kc * 16 + hh * 8;
      float4 ta = *(const float4*)tp;
      float4 tb = *(const float4*)(tp + 4);
      bf16x8 w;
      w[0] = (__bf16)__expf(ta.x); w[1] = (__bf16)__expf(ta.y);
      w[2] = (__bf16)__expf(ta.z); w[3] = (__bf16)__expf(ta.w);
      w[4] = (__bf16)__expf(tb.x); w[5] = (__bf16)__expf(tb.y);
      w[6] = (__bf16)__expf(tb.z); w[7] = (__bf16)__expf(tb.w);
      Wb[ma][kc] = w;
    }
  }

  const int c0 = lane & 31;
  float lsres = 0.0f, redmax_r = 1.0f;
  int cur = 0;
  for (int k = 0; k < ke; ++k) {
    float scf = 1.0f;
    if ((k & 7) == 0 && k != 0) {
      scf = __builtin_amdgcn_rcpf(redmax_r);
      lsres += __logf(redmax_r);
    }
    const __bf16* Pc = W.P[cur];
    f32x16 a00, a01, a10, a11;
#pragma unroll
    for (int e = 0; e < 16; ++e) { a00[e] = 0; a01[e] = 0; a10[e] = 0; a11[e] = 0; }
#pragma unroll
    for (int kc = 0; kc < 4; ++kc) {
      bf16x8 B0 = *(const bf16x8*)(Pc + c0 * 68 + kc * 16 + hh * 8);
      bf16x8 B1 = *(const bf16x8*)(Pc + (32 + c0) * 68 + kc * 16 + hh * 8);
      a00 = __builtin_amdgcn_mfma_f32_32x32x16_bf16(Wb[0][kc], B0, a00, 0, 0, 0);
      a01 = __builtin_amdgcn_mfma_f32_32x32x16_bf16(Wb[0][kc], B1, a01, 0, 0, 0);
      a10 = __builtin_amdgcn_mfma_f32_32x32x16_bf16(Wb[1][kc], B0, a10, 0, 0, 0);
      a11 = __builtin_amdgcn_mfma_f32_32x32x16_bf16(Wb[1][kc], B1, a11, 0, 0, 0);
    }
    __bf16* Pn = W.P[cur ^ 1];
    const bool track = ((k & 7) == 7);
    float mx = 0.0f;  // all entries >= 0
#pragma unroll
    for (int q = 0; q < 4; ++q) {  // ma = 0
      const int i0 = 8 * q + 4 * hh;
      bf16x4 ev = *(const bf16x4*)&W.xs[k][i0];
      bf16x4 w0, w1;
#pragma unroll
      for (int j = 0; j < 4; ++j) {
        float ef = (float)ev[j] * scf;
        float s0 = a00[4 * q + j] * ef;
        float s1 = a01[4 * q + j] * ef;
        if (track) mx = fmaxf(mx, fmaxf(s0, s1));
        w0[j] = (__bf16)s0; w1[j] = (__bf16)s1;
      }
      *(bf16x4*)(Pn + c0 * 68 + i0) = w0;
      *(bf16x4*)(Pn + (32 + c0) * 68 + i0) = w1;
    }
#pragma unroll
    for (int q = 0; q < 4; ++q) {  // ma = 1
      const int i0 = 32 + 8 * q + 4 * hh;
      bf16x4 ev = *(const bf16x4*)&W.xs[k][i0];
      bf16x4 w0, w1;
#pragma unroll
      for (int j = 0; j < 4; ++j) {
        float ef = (float)ev[j] * scf;
        float s0 = a10[4 * q + j] * ef;
        float s1 = a11[4 * q + j] * ef;
        if (track) mx = fmaxf(mx, fmaxf(s0, s1));
        w0[j] = (__bf16)s0; w1[j] = (__bf16)s1;
      }
      *(bf16x4*)(Pn + c0 * 68 + i0) = w0;
      *(bf16x4*)(Pn + (32 + c0) * 68 + i0) = w1;
    }
    if (track) redmax_r = wave_max64(mx);
    cur ^= 1;
  }
  // write M_seg (bf16, G[n*64+k] = M[k][n]) + log-scale
  __bf16* G = ((__bf16*)ws) + (size_t)sid * 4096;
  const __bf16* Pf = W.P[cur];
  for (int i = lane; i < 4096; i += 64) G[i] = Pf[(i >> 6) * 68 + (i & 63)];
  float mt = (lane < ke) ? W.m[lane] : 0.0f;
  float msum = wave_sum64(mt);
  if (lane == 0) scales[sid] = msum + lsres;
}

// K2: per-batch scan over 32 segment matrices (wave0 compute, wave1 stage).
__global__ __launch_bounds__(128) void asg_k2(const float* __restrict__ inputs,
                                              char* __restrict__ ws) {
  __shared__ __align__(16) float Gl[2][64][68];
  __shared__ __align__(16) float Eb[64];
  const int tid = threadIdx.x, lane = tid & 63, wv = tid >> 6;
  const int b = blockIdx.x;
  const __bf16* M = (const __bf16*)ws;
  const float* scales = (const float*)(ws + OFF_SCALE);
  float* full = (float*)(ws + OFF_FULL);

  auto stage = [&](int s, int buf) {
    const __bf16* g = M + ((size_t)(b * NSEG + s)) * 4096 + lane * 64;
#pragma unroll
    for (int q = 0; q < 8; ++q) {
      bf16x8 v = *(const bf16x8*)(g + q * 8);
      float4 f0{(float)v[0], (float)v[1], (float)v[2], (float)v[3]};
      float4 f1{(float)v[4], (float)v[5], (float)v[6], (float)v[7]};
      *(float4*)&Gl[buf][lane][q * 8] = f0;
      *(float4*)&Gl[buf][lane][q * 8 + 4] = f1;
    }
  };

  float Ev = 0.0f, ls = 0.0f;
  if (wv == 0) {
    float x0 = inputs[b * L_ + lane];
    float m0 = wave_max64(x0);
    Ev = __expf(x0 - m0);
    ls = m0;
    Eb[lane] = Ev;
  } else {
    stage(0, 0);
  }
  __syncthreads();
  for (int s = 0; s < NSEG; ++s) {
    if (wv == 1 && s + 1 < NSEG) stage(s + 1, (s + 1) & 1);
    if (wv == 0) {
      const int buf = s & 1;
      float ap0 = 0, ap1 = 0, ap2 = 0, ap3 = 0;
#pragma unroll
      for (int k4 = 0; k4 < 16; ++k4) {
        float4 e4 = *(const float4*)&Eb[k4 * 4];
        ap0 = fmaf(Gl[buf][4 * k4 + 0][lane], e4.x, ap0);
        ap1 = fmaf(Gl[buf][4 * k4 + 1][lane], e4.y, ap1);
        ap2 = fmaf(Gl[buf][4 * k4 + 2][lane], e4.z, ap2);
        ap3 = fmaf(Gl[buf][4 * k4 + 3][lane], e4.w, ap3);
      }
      float ap = (ap0 + ap1) + (ap2 + ap3);
      float mx = wave_max64(ap);
      float sc = __builtin_amdgcn_rcpf(mx);
      Ev = ap * sc;
      Eb[lane] = Ev;
      ls += __logf(mx) + scales[b * NSEG + s];
    }
    __syncthreads();
  }
  if (wv == 0) {
    float ssum = wave_sum64(Ev);
    if (lane == 0) full[b] = ls + __logf(ssum);
  }
}

// K3: per-batch dot(fwd,bwd) in f64, log-combine, mean over batches.
__global__ __launch_bounds__(256) void asg_k3(const char* __restrict__ ws,
                                              float* __restrict__ out) {
  __shared__ float diff[64];
  const int tid = threadIdx.x;
  const int b = tid >> 2, q = tid & 3;
  const double* fv = (const double*)(ws + OFF_FWD) + b * 256;
  const double* bv = (const double*)(ws + OFF_BWD) + b * 256;
  const float* full = (const float*)(ws + OFF_FULL);
  const float* Lf = (const float*)(ws + OFF_LF);
  const float* Lb = (const float*)(ws + OFF_LB);

  double s = 0.0;
  for (int j = q * 64; j < q * 64 + 64; ++j) s += fv[j] * bv[j];
  s += __shfl_xor(s, 1, 64);
  s += __shfl_xor(s, 2, 64);
  if (q == 0) {
    s = fmax(s, 1e-300);
    long long ls = __double_as_longlong(s);
    int ex = (int)((ls >> 52) & 0x7FF);
    double mant = __longlong_as_double((ls & 0xFFFFFFFFFFFFFLL) |
                                       (1023LL << 52));
    float alig = Lf[b] + Lb[b] + (float)(ex - 1023) * LN2 + __logf((float)mant);
    diff[b] = full[b] - alig;
  }
  __syncthreads();
  if (tid < 64) {
    float d = diff[tid];
    d = wave_sum64(d);
    if (tid == 0) out[0] = d * (1.0f / 64.0f);
  }
}

extern "C" void kernel_launch(void* const* d_in, const int* in_sizes, int n_in,
                              void* d_out, int out_size, void* d_ws,
                              size_t ws_size, hipStream_t stream) {
  const float* inputs = (const float*)d_in[0];
  const float* trans = (const float*)d_in[1];
  const int* targets = (const int*)d_in[2];
  const int* ilen = (const int*)d_in[3];
  const int* tlen = (const int*)d_in[4];
  char* ws = (char*)d_ws;
  float* out = (float*)d_out;

  hipLaunchKernelGGL(asg_k1, dim3(2 * B_ + NSEG * B_ / 2), dim3(256), 0,
                     stream, inputs, trans, targets, ilen, tlen, ws);
  hipLaunchKernelGGL(asg_k2, dim3(B_), dim3(128), 0, stream, inputs, ws);
  hipLaunchKernelGGL(asg_k3, dim3(1), dim3(256), 0, stream, ws, out);
}

// Round 11
// 195.507 us; speedup vs baseline: 2.0120x; 2.0120x over previous
//
#include <hip/hip_runtime.h>
#include <math.h>

// ASG loss, MI355X. inputs (T,B,L) f32, trans (L,L) f32, targets (B,S) i32,
// input_lengths (B,) i32, target_lengths (B,) i32. out = mean(full - aligned).
//
// asg_k1 (2176 blocks x 256, LDS ~26.4KB -> 6 blocks/CU):
//   blocks 0..63    : fac FORWARD chain, t = 1..TS (exp domain, f64 states)
//   blocks 64..127  : fac BACKWARD chain, t = len-1..TS+1 (transposed recur.)
//   blocks 128..2175: fcc phase 1 — 64-step segment transfer-matrix products
//     on MFMA (4-wave cooperative, exp domain, row-max + lag-8 rescale);
//     xs staged as bf16.
//   fac waves: wv0 compute (setprio 2), wv1 stage global->E (f16) + rowmax,
//   wv2 regather E->Eg (f16, compute layout) + rowmax copy.
// asg_k2 (64 blocks): per-batch scan over 32 segment matrices + LSE.
// asg_k3 (1 block): per-batch dot(fwd,bwd) in f64 + log + mean combine.
// NOTE: needs ~17.1 MB of d_ws.

constexpr int T_ = 2048, B_ = 64, L_ = 64, S_ = 256;
constexpr int CSEG = 64, NSEG = 32;  // fcc segments cover t = 1..2047
constexpr int FCH = 16;              // fac chunk rows
constexpr float LN2 = 0.6931471805599453f;

typedef __bf16 bf16x8 __attribute__((ext_vector_type(8)));
typedef __bf16 bf16x4 __attribute__((ext_vector_type(4)));
typedef float f32x16 __attribute__((ext_vector_type(16)));
typedef _Float16 f16x4 __attribute__((ext_vector_type(4)));

constexpr size_t OFF_SCALE = (size_t)NSEG * B_ * 4096 * 2;  // 16 MB M_seg
constexpr size_t OFF_FULL = OFF_SCALE + (size_t)NSEG * B_ * 4;
constexpr size_t OFF_FWD = OFF_FULL + B_ * 4;
constexpr size_t OFF_BWD = OFF_FWD + (size_t)B_ * 256 * 8;
constexpr size_t OFF_LF = OFF_BWD + (size_t)B_ * 256 * 8;
constexpr size_t OFF_LB = OFF_LF + B_ * 4;

__device__ __forceinline__ float wave_max64(float v) {
#pragma unroll
  for (int off = 1; off < 64; off <<= 1) v = fmaxf(v, __shfl_xor(v, off, 64));
  return v;
}
__device__ __forceinline__ float wave_sum64(float v) {
#pragma unroll
  for (int off = 1; off < 64; off <<= 1) v += __shfl_xor(v, off, 64);
  return v;
}
__device__ __forceinline__ double wave_max64d(double v) {
#pragma unroll
  for (int off = 1; off < 64; off <<= 1) v = fmax(v, __shfl_xor(v, off, 64));
  return v;
}

struct P1shm {
  __align__(16) __bf16 xs[CSEG][68];   // exp(x_t - m_t) bf16, 8.7 KB
  __align__(16) float m_arr[CSEG];
  __align__(16) float redmax[4];
  __align__(16) __bf16 P[2][64 * 68];  // col-major, stride 68, 17.4 KB
};
struct FACshm {
  __align__(16) _Float16 E[2][FCH][68];    // exp(x - m_row) f16, 4.4 KB
  __align__(16) _Float16 Eg[2][FCH][256];  // gathered, compute layout, 16 KB
  __align__(16) float m_fac[2][FCH];       // row maxes (stage-side)
  __align__(16) float mg[2][FCH];          // row maxes (compute-side copy)
};
union KU {
  P1shm p1;
  FACshm fac;
};

__global__ __launch_bounds__(256) void asg_k1(
    const float* __restrict__ inputs, const float* __restrict__ trans,
    const int* __restrict__ targets, const int* __restrict__ ilen,
    const int* __restrict__ tlenp, char* __restrict__ ws) {
  __shared__ KU u;
  const int tid = threadIdx.x, lane = tid & 63, wv = tid >> 6;
  const int bid = blockIdx.x;
  float* scales = (float*)(ws + OFF_SCALE);

  if (bid < 2 * B_) {
    // ================== FAC half-chains (exp domain, f64) ==================
    const bool isfwd = (bid < B_);
    const int b = bid & 63;
    const int len = ilen[b];
    const int tl = tlenp[b];
    const int TS = (len - 1) >> 1;
    double* vecout = (double*)(ws + (isfwd ? OFF_FWD : OFF_BWD)) + b * 256;
    float* Lout = (float*)(ws + (isfwd ? OFF_LF : OFF_LB));

    int tg0 = 0, tg1 = 0, tg2 = 0, tg3 = 0;
    if (wv == 0 || wv == 2) {
      int4 t4 = *(const int4*)(targets + b * S_ + lane * 4);
      tg0 = t4.x; tg1 = t4.y; tg2 = t4.z; tg3 = t4.w;
    }
    auto stage = [&](int c, int buf) {  // wave1: global -> E (f16), rowmax
#pragma unroll
      for (int i = 0; i < 4; ++i) {
        int f = lane + 64 * i;
        int r = f >> 4, c4 = f & 15;
        int t = c * FCH + r;
        if (t > T_ - 1) t = T_ - 1;
        float4 v = *(const float4*)(inputs + (size_t)t * (B_ * L_) + b * L_ +
                                    c4 * 4);
        float m = fmaxf(fmaxf(v.x, v.y), fmaxf(v.z, v.w));
#pragma unroll
        for (int off = 1; off < 16; off <<= 1)
          m = fmaxf(m, __shfl_xor(m, off, 64));
        f16x4 h;
        h[0] = (_Float16)__expf(v.x - m); h[1] = (_Float16)__expf(v.y - m);
        h[2] = (_Float16)__expf(v.z - m); h[3] = (_Float16)__expf(v.w - m);
        *(f16x4*)&u.fac.E[buf][r][c4 * 4] = h;
        if ((lane & 15) == 0) u.fac.m_fac[buf][r] = m;
      }
    };
    auto regather = [&](int c, int buf) {  // wave2: E -> Eg (compute layout)
#pragma unroll 4
      for (int r = 0; r < FCH; ++r) {
        f16x4 h;
        h[0] = u.fac.E[buf][r][tg0]; h[1] = u.fac.E[buf][r][tg1];
        h[2] = u.fac.E[buf][r][tg2]; h[3] = u.fac.E[buf][r][tg3];
        *(f16x4*)&u.fac.Eg[buf][r][lane * 4] = h;
      }
      if (lane < FCH) u.fac.mg[buf][lane] = u.fac.m_fac[buf][lane];
    };

    if (isfwd) {
      // ---------------- FORWARD: t = 1..TS ----------------
      double sw0 = 0, sw1 = 0, sw2 = 0, sw3 = 0;
      double mw0 = 0, mw1 = 0, mw2 = 0, mw3 = 0;
      if (wv == 0) {
        int tgm1 = (lane > 0) ? targets[b * S_ + lane * 4 - 1] : 0;
        sw0 = exp((double)trans[tg0 * 64 + tg0]);
        sw1 = exp((double)trans[tg1 * 64 + tg1]);
        sw2 = exp((double)trans[tg2 * 64 + tg2]);
        sw3 = exp((double)trans[tg3 * 64 + tg3]);
        mw0 = (lane == 0) ? 0.0 : exp((double)trans[tg0 * 64 + tgm1]);
        mw1 = exp((double)trans[tg1 * 64 + tg0]);
        mw2 = exp((double)trans[tg2 * 64 + tg1]);
        mw3 = exp((double)trans[tg3 * 64 + tg2]);
      }
      if (wv == 1) { stage(0, 0); stage(1, 1); }
      __syncthreads();
      if (wv == 2) regather(0, 0);
      __syncthreads();

      double d0 = 0.0, d1 = 0.0, d2 = 0.0, d3 = 0.0, shv = 0.0;
      float Lacc = 0.0f;
      const int addr_up = ((lane + 63) & 63) << 2;
      if (wv == 0) {
        if (lane == 0) d0 = (double)(float)u.fac.Eg[0][0][0];
        Lacc = u.fac.mg[0][0];
        __builtin_amdgcn_s_setprio(2);
      }
      for (int c = 0; 16 * c <= TS; ++c) {
        const int buf = c & 1;
        if (wv == 1) {
          if (16 * (c + 2) <= TS) stage(c + 2, buf);
        } else if (wv == 2) {
          if (16 * (c + 1) <= TS) regather(c + 1, buf ^ 1);
        } else if (wv == 0) {
          if (c) {  // exact power-of-2 rescale
            double dmax = wave_max64d(fmax(fmax(d0, d1), fmax(d2, d3)));
            long long lm = __double_as_longlong(dmax);
            int ex = (int)((lm >> 52) & 0x7FF);
            double M = __longlong_as_double((long long)(2046 - ex) << 52);
            d0 *= M; d1 *= M; d2 *= M; d3 *= M; shv *= M;
            Lacc += (float)(ex - 1023) * LN2;
          }
          const int r0 = (c == 0) ? 1 : 0;
          const int rmax = min(FCH, TS + 1 - 16 * c);
          f16x4 eH = *(const f16x4*)&u.fac.Eg[buf][r0][lane * 4];
          float mH = u.fac.mg[buf][r0];
          const int r1 = min(r0 + 1, FCH - 1);
          f16x4 pH = *(const f16x4*)&u.fac.Eg[buf][r1][lane * 4];
          float pM = u.fac.mg[buf][r1];
          for (int r = r0; r < rmax; ++r) {
            const int rn = min(r + 2, FCH - 1);
            f16x4 nH = *(const f16x4*)&u.fac.Eg[buf][rn][lane * 4];
            float nM = u.fac.mg[buf][rn];
            double nd3 = (double)(float)eH[3] * fma(mw3, d2, sw3 * d3);
            long long l3 = __double_as_longlong(nd3);
            int slo = __builtin_amdgcn_ds_bpermute(addr_up, (int)l3);
            int shi = __builtin_amdgcn_ds_bpermute(addr_up, (int)(l3 >> 32));
            double nd0 = (double)(float)eH[0] * fma(mw0, shv, sw0 * d0);
            double nd1 = (double)(float)eH[1] * fma(mw1, d0, sw1 * d1);
            double nd2 = (double)(float)eH[2] * fma(mw2, d1, sw2 * d2);
            d0 = nd0; d1 = nd1; d2 = nd2; d3 = nd3;
            shv = __longlong_as_double(((long long)shi << 32) |
                                       (unsigned int)slo);
            Lacc += mH;
            eH = pH; mH = pM; pH = nH; pM = nM;
          }
        }
        __syncthreads();
      }
      if (wv == 0) {
        __builtin_amdgcn_s_setprio(0);
        vecout[lane * 4 + 0] = d0; vecout[lane * 4 + 1] = d1;
        vecout[lane * 4 + 2] = d2; vecout[lane * 4 + 3] = d3;
        if (lane == 0) Lout[b] = Lacc;
      }
    } else {
      // ---------------- BACKWARD: t = len-1..TS+1 (transposed) ----------
      double sw0 = 0, sw1 = 0, sw2 = 0, sw3 = 0;
      double mv0 = 0, mv1 = 0, mv2 = 0, mv3 = 0;
      if (wv == 0) {
        int tg4 = (lane < 63) ? targets[b * S_ + lane * 4 + 4] : 0;
        sw0 = exp((double)trans[tg0 * 64 + tg0]);
        sw1 = exp((double)trans[tg1 * 64 + tg1]);
        sw2 = exp((double)trans[tg2 * 64 + tg2]);
        sw3 = exp((double)trans[tg3 * 64 + tg3]);
        mv0 = exp((double)trans[tg1 * 64 + tg0]);
        mv1 = exp((double)trans[tg2 * 64 + tg1]);
        mv2 = exp((double)trans[tg3 * 64 + tg2]);
        mv3 = (lane < 63) ? exp((double)trans[tg4 * 64 + tg3]) : 0.0;
      }
      const int cmax = (len - 1) >> 4;
      const int cmin = (TS + 1) >> 4;
      if (wv == 1) {
        stage(cmax, cmax & 1);
        if (cmax - 1 >= cmin) stage(cmax - 1, (cmax - 1) & 1);
      }
      __syncthreads();
      if (wv == 2) regather(cmax, cmax & 1);
      __syncthreads();

      const int idx = tl - 1;
      double b0 = 0, b1 = 0, b2 = 0, b3 = 0, g0cur = 0, shg = 0;
      float Lacc = 0.0f;
      const int addr_dn = ((lane + 1) & 63) << 2;
      if (wv == 0) {
        b0 = (lane * 4 + 0 == idx) ? 1.0 : 0.0;
        b1 = (lane * 4 + 1 == idx) ? 1.0 : 0.0;
        b2 = (lane * 4 + 2 == idx) ? 1.0 : 0.0;
        b3 = (lane * 4 + 3 == idx) ? 1.0 : 0.0;
        const int rh0 = (len - 1) & 15;
        float e0x = (float)u.fac.Eg[cmax & 1][rh0][lane * 4];
        g0cur = (double)e0x * b0;
        long long lg = __double_as_longlong(g0cur);
        int slo = __builtin_amdgcn_ds_bpermute(addr_dn, (int)lg);
        int shi = __builtin_amdgcn_ds_bpermute(addr_dn, (int)(lg >> 32));
        shg = __longlong_as_double(((long long)shi << 32) | (unsigned int)slo);
        __builtin_amdgcn_s_setprio(2);
      }
      for (int c = cmax; c >= cmin; --c) {
        const int buf = c & 1;
        if (wv == 1) {
          if (c - 2 >= cmin) stage(c - 2, buf);
        } else if (wv == 2) {
          if (c - 1 >= cmin) regather(c - 1, buf ^ 1);
        } else if (wv == 0) {
          if (c != cmax) {
            double dmax = wave_max64d(fmax(fmax(b0, b1), fmax(b2, b3)));
            long long lm = __double_as_longlong(dmax);
            int ex = (int)((lm >> 52) & 0x7FF);
            double M = __longlong_as_double((long long)(2046 - ex) << 52);
            b0 *= M; b1 *= M; b2 *= M; b3 *= M; g0cur *= M; shg *= M;
            Lacc += (float)(ex - 1023) * LN2;
          }
          const int rhi = (c == cmax) ? ((len - 1) & 15) : FCH - 1;
          const int rlo = max(0, (TS + 1) - 16 * c);
          f16x4 eH = *(const f16x4*)&u.fac.Eg[buf][rhi][lane * 4];
          float mH = u.fac.mg[buf][rhi];
          const int r1 = max(rhi - 1, rlo);
          f16x4 pH = *(const f16x4*)&u.fac.Eg[buf][r1][lane * 4];
          float pM = u.fac.mg[buf][r1];
          for (int r = rhi; r >= rlo; --r) {
            const int rn = max(r - 2, rlo);
            f16x4 nH = *(const f16x4*)&u.fac.Eg[buf][rn][lane * 4];
            float nM = u.fac.mg[buf][rn];
            double g1 = (double)(float)eH[1] * b1;
            double g2 = (double)(float)eH[2] * b2;
            double g3 = (double)(float)eH[3] * b3;
            double nb0 = fma(mv0, g1, sw0 * g0cur);
            double nb1 = fma(mv1, g2, sw1 * g1);
            double nb2 = fma(mv2, g3, sw2 * g2);
            double nb3 = fma(mv3, shg, sw3 * g3);
            double g0n = (double)(float)pH[0] * nb0;
            long long lg2 = __double_as_longlong(g0n);
            int slo2 = __builtin_amdgcn_ds_bpermute(addr_dn, (int)lg2);
            int shi2 = __builtin_amdgcn_ds_bpermute(addr_dn, (int)(lg2 >> 32));
            b0 = nb0; b1 = nb1; b2 = nb2; b3 = nb3;
            g0cur = g0n;
            shg = __longlong_as_double(((long long)shi2 << 32) |
                                       (unsigned int)slo2);
            Lacc += mH;
            eH = pH; mH = pM; pH = nH; pM = nM;
          }
        }
        __syncthreads();
      }
      if (wv == 0) {
        __builtin_amdgcn_s_setprio(0);
        vecout[lane * 4 + 0] = b0; vecout[lane * 4 + 1] = b1;
        vecout[lane * 4 + 2] = b2; vecout[lane * 4 + 3] = b3;
        if (lane == 0) Lout[b] = Lacc;
      }
    }
    return;
  }

  // ========================= FCC PHASE 1 (MFMA, 4-wave) =========================
  const int sid = bid - 2 * B_;
  const int b = sid >> 5, s = sid & 31;
  const int t0 = 1 + s * CSEG;
  const int len = ilen[b];
  int ke = min(CSEG, T_ - t0);
  ke = min(ke, len - t0);
  if (ke < 0) ke = 0;

  // stage xs = bf16(exp(x - rowmax)); rowmax in m_arr
#pragma unroll
  for (int i = 0; i < 4; ++i) {
    int f4 = tid + 256 * i;
    int r = f4 >> 4, c4 = f4 & 15;
    int t = t0 + r;
    if (t > T_ - 1) t = T_ - 1;
    float4 v = *(const float4*)(inputs + (size_t)t * (B_ * L_) + b * L_ + c4 * 4);
    float m = fmaxf(fmaxf(v.x, v.y), fmaxf(v.z, v.w));
#pragma unroll
    for (int off = 1; off < 16; off <<= 1)
      m = fmaxf(m, __shfl_xor(m, off, 64));
    bf16x4 h;
    h[0] = (__bf16)__expf(v.x - m); h[1] = (__bf16)__expf(v.y - m);
    h[2] = (__bf16)__expf(v.z - m); h[3] = (__bf16)__expf(v.w - m);
    *(bf16x4*)&u.p1.xs[r][c4 * 4] = h;
    if ((lane & 15) == 0) u.p1.m_arr[r] = m;
  }
  for (int i = tid; i < 64 * 68; i += 256) u.p1.P[0][i] = (__bf16)0.0f;
  __syncthreads();
  if (tid < 64) u.p1.P[0][tid * 68 + tid] = (__bf16)1.0f;

  const int ma = wv >> 1, nb = wv & 1;
  const int arow = 32 * ma + (lane & 31);
  const int hh = lane >> 5;
  const int coln = 32 * nb + (lane & 31);
  float Wf[4][8];
#pragma unroll
  for (int kc = 0; kc < 4; ++kc) {
    const float* tp = trans + arow * 64 + kc * 16 + hh * 8;
#pragma unroll
    for (int j = 0; j < 8; ++j) Wf[kc][j] = __expf(tp[j]);
  }

  float lsres = 0.0f;
  int cur = 0;
  for (int k = 0; k < ke; ++k) {
    __syncthreads();
    float scf = 1.0f;
    if ((k & 7) == 0 && k != 0) {
      float mm = fmaxf(fmaxf(u.p1.redmax[0], u.p1.redmax[1]),
                       fmaxf(u.p1.redmax[2], u.p1.redmax[3]));
      scf = __builtin_amdgcn_rcpf(mm);
      lsres += __logf(mm);
    }
    const float srow = (float)u.p1.xs[k][arow] * scf;
    bf16x8 A[4], Bf[4];
    const __bf16* Pc = u.p1.P[cur];
#pragma unroll
    for (int kc = 0; kc < 4; ++kc) {
#pragma unroll
      for (int j = 0; j < 8; ++j) A[kc][j] = (__bf16)(Wf[kc][j] * srow);
      const __bf16* p = Pc + coln * 68 + kc * 16 + hh * 8;
      bf16x4 lo = *(const bf16x4*)p;
      bf16x4 hi = *(const bf16x4*)(p + 4);
      Bf[kc] = __builtin_shufflevector(lo, hi, 0, 1, 2, 3, 4, 5, 6, 7);
    }
    f32x16 acc;
#pragma unroll
    for (int e = 0; e < 16; ++e) acc[e] = 0.0f;
    acc = __builtin_amdgcn_mfma_f32_32x32x16_bf16(A[0], Bf[0], acc, 0, 0, 0);
    acc = __builtin_amdgcn_mfma_f32_32x32x16_bf16(A[1], Bf[1], acc, 0, 0, 0);
    acc = __builtin_amdgcn_mfma_f32_32x32x16_bf16(A[2], Bf[2], acc, 0, 0, 0);
    acc = __builtin_amdgcn_mfma_f32_32x32x16_bf16(A[3], Bf[3], acc, 0, 0, 0);
    __bf16* Pn = u.p1.P[cur ^ 1];
#pragma unroll
    for (int q = 0; q < 4; ++q) {
      const int i0 = 32 * ma + 8 * q + 4 * hh;
      bf16x4 w;
      w[0] = (__bf16)acc[4 * q + 0]; w[1] = (__bf16)acc[4 * q + 1];
      w[2] = (__bf16)acc[4 * q + 2]; w[3] = (__bf16)acc[4 * q + 3];
      *(bf16x4*)(Pn + coln * 68 + i0) = w;
    }
    if ((k & 7) == 7) {
      float mx = acc[0];
#pragma unroll
      for (int e = 1; e < 16; ++e) mx = fmaxf(mx, acc[e]);
      mx = wave_max64(mx);
      if (lane == 0) u.p1.redmax[wv] = mx;
    }
    cur ^= 1;
  }
  __syncthreads();
  __bf16* G = ((__bf16*)ws) + (size_t)sid * 4096;
  const __bf16* Pf = u.p1.P[cur];
  for (int i = tid; i < 4096; i += 256) G[i] = Pf[(i >> 6) * 68 + (i & 63)];
  if (wv == 0) {
    float mt = (lane < ke) ? u.p1.m_arr[lane] : 0.0f;
    float msum = wave_sum64(mt);
    if (lane == 0) scales[sid] = msum + lsres;
  }
}

// K2: per-batch scan over 32 segment matrices (wave0 compute, wave1 stage).
__global__ __launch_bounds__(128) void asg_k2(const float* __restrict__ inputs,
                                              char* __restrict__ ws) {
  __shared__ __align__(16) float Gl[2][64][68];
  __shared__ __align__(16) float Eb[64];
  const int tid = threadIdx.x, lane = tid & 63, wv = tid >> 6;
  const int b = blockIdx.x;
  const __bf16* M = (const __bf16*)ws;
  const float* scales = (const float*)(ws + OFF_SCALE);
  float* full = (float*)(ws + OFF_FULL);

  auto stage = [&](int s, int buf) {
    const __bf16* g = M + ((size_t)(b * NSEG + s)) * 4096 + lane * 64;
#pragma unroll
    for (int q = 0; q < 8; ++q) {
      bf16x8 v = *(const bf16x8*)(g + q * 8);
      float4 f0{(float)v[0], (float)v[1], (float)v[2], (float)v[3]};
      float4 f1{(float)v[4], (float)v[5], (float)v[6], (float)v[7]};
      *(float4*)&Gl[buf][lane][q * 8] = f0;
      *(float4*)&Gl[buf][lane][q * 8 + 4] = f1;
    }
  };

  float Ev = 0.0f, ls = 0.0f;
  if (wv == 0) {
    float x0 = inputs[b * L_ + lane];
    float m0 = wave_max64(x0);
    Ev = __expf(x0 - m0);
    ls = m0;
    Eb[lane] = Ev;
  } else {
    stage(0, 0);
  }
  __syncthreads();
  for (int s = 0; s < NSEG; ++s) {
    if (wv == 1 && s + 1 < NSEG) stage(s + 1, (s + 1) & 1);
    if (wv == 0) {
      const int buf = s & 1;
      float ap0 = 0, ap1 = 0, ap2 = 0, ap3 = 0;
#pragma unroll
      for (int k4 = 0; k4 < 16; ++k4) {
        float4 e4 = *(const float4*)&Eb[k4 * 4];
        ap0 = fmaf(Gl[buf][4 * k4 + 0][lane], e4.x, ap0);
        ap1 = fmaf(Gl[buf][4 * k4 + 1][lane], e4.y, ap1);
        ap2 = fmaf(Gl[buf][4 * k4 + 2][lane], e4.z, ap2);
        ap3 = fmaf(Gl[buf][4 * k4 + 3][lane], e4.w, ap3);
      }
      float ap = (ap0 + ap1) + (ap2 + ap3);
      float mx = wave_max64(ap);
      float sc = __builtin_amdgcn_rcpf(mx);
      Ev = ap * sc;
      Eb[lane] = Ev;
      ls += __logf(mx) + scales[b * NSEG + s];
    }
    __syncthreads();
  }
  if (wv == 0) {
    float ssum = wave_sum64(Ev);
    if (lane == 0) full[b] = ls + __logf(ssum);
  }
}

// K3: per-batch dot(fwd,bwd) in f64, log-combine, mean over batches.
__global__ __launch_bounds__(256) void asg_k3(const char* __restrict__ ws,
                                              float* __restrict__ out) {
  __shared__ float diff[64];
  const int tid = threadIdx.x;
  const int b = tid >> 2, q = tid & 3;
  const double* fv = (const double*)(ws + OFF_FWD) + b * 256;
  const double* bv = (const double*)(ws + OFF_BWD) + b * 256;
  const float* full = (const float*)(ws + OFF_FULL);
  const float* Lf = (const float*)(ws + OFF_LF);
  const float* Lb = (const float*)(ws + OFF_LB);

  double s = 0.0;
  for (int j = q * 64; j < q * 64 + 64; ++j) s += fv[j] * bv[j];
  s += __shfl_xor(s, 1, 64);
  s += __shfl_xor(s, 2, 64);
  if (q == 0) {
    s = fmax(s, 1e-300);
    long long ls = __double_as_longlong(s);
    int ex = (int)((ls >> 52) & 0x7FF);
    double mant = __longlong_as_double((ls & 0xFFFFFFFFFFFFFLL) |
                                       (1023LL << 52));
    float alig = Lf[b] + Lb[b] + (float)(ex - 1023) * LN2 + __logf((float)mant);
    diff[b] = full[b] - alig;
  }
  __syncthreads();
  if (tid < 64) {
    float d = diff[tid];
    d = wave_sum64(d);
    if (tid == 0) out[0] = d * (1.0f / 64.0f);
  }
}

extern "C" void kernel_launch(void* const* d_in, const int* in_sizes, int n_in,
                              void* d_out, int out_size, void* d_ws,
                              size_t ws_size, hipStream_t stream) {
  const float* inputs = (const float*)d_in[0];
  const float* trans = (const float*)d_in[1];
  const int* targets = (const int*)d_in[2];
  const int* ilen = (const int*)d_in[3];
  const int* tlen = (const int*)d_in[4];
  char* ws = (char*)d_ws;
  float* out = (float*)d_out;

  hipLaunchKernelGGL(asg_k1, dim3(2 * B_ + NSEG * B_), dim3(256), 0, stream,
                     inputs, trans, targets, ilen, tlen, ws);
  hipLaunchKernelGGL(asg_k2, dim3(B_), dim3(128), 0, stream, inputs, ws);
  hipLaunchKernelGGL(asg_k3, dim3(1), dim3(256), 0, stream, ws, out);
}

// Round 12
// 194.645 us; speedup vs baseline: 2.0210x; 1.0044x over previous
//
#include <hip/hip_runtime.h>
#include <math.h>

// ASG loss, MI355X. inputs (T,B,L) f32, trans (L,L) f32, targets (B,S) i32,
// input_lengths (B,) i32, target_lengths (B,) i32. out = mean(full - aligned).
//
// asg_k1 (2176 blocks x 256, LDS ~26.4KB -> 6 blocks/CU):
//   blocks 0..63    : fac FORWARD chain, t = 1..TS (exp domain, f64 states)
//   blocks 64..127  : fac BACKWARD chain, t = len-1..TS+1 (transposed recur.)
//   blocks 128..2175: fcc phase 1 — 64-step segment transfer-matrix products
//     on MFMA (4-wave cooperative, exp domain, row-max + lag-8 rescale);
//     xs staged as bf16.
//   fac waves: wv0 compute (setprio 2), wv1 stage global->E (f16) + rowmax,
//   wv2 regather E->Eg (f16, compute layout) + rowmax copy.
// asg_k2 (64 blocks): per-batch scan over 32 segment matrices + LSE.
// asg_k3 (1 block): per-batch dot(fwd,bwd) in f64 + log + mean combine.
// NOTE: needs ~17.1 MB of d_ws.

constexpr int T_ = 2048, B_ = 64, L_ = 64, S_ = 256;
constexpr int CSEG = 64, NSEG = 32;  // fcc segments cover t = 1..2047
constexpr int FCH = 16;              // fac chunk rows
constexpr float LN2 = 0.6931471805599453f;

typedef __bf16 bf16x8 __attribute__((ext_vector_type(8)));
typedef __bf16 bf16x4 __attribute__((ext_vector_type(4)));
typedef float f32x16 __attribute__((ext_vector_type(16)));
typedef _Float16 f16x4 __attribute__((ext_vector_type(4)));

constexpr size_t OFF_SCALE = (size_t)NSEG * B_ * 4096 * 2;  // 16 MB M_seg
constexpr size_t OFF_FULL = OFF_SCALE + (size_t)NSEG * B_ * 4;
constexpr size_t OFF_FWD = OFF_FULL + B_ * 4;
constexpr size_t OFF_BWD = OFF_FWD + (size_t)B_ * 256 * 8;
constexpr size_t OFF_LF = OFF_BWD + (size_t)B_ * 256 * 8;
constexpr size_t OFF_LB = OFF_LF + B_ * 4;

__device__ __forceinline__ float wave_max64(float v) {
#pragma unroll
  for (int off = 1; off < 64; off <<= 1) v = fmaxf(v, __shfl_xor(v, off, 64));
  return v;
}
__device__ __forceinline__ float wave_sum64(float v) {
#pragma unroll
  for (int off = 1; off < 64; off <<= 1) v += __shfl_xor(v, off, 64);
  return v;
}
__device__ __forceinline__ double wave_max64d(double v) {
#pragma unroll
  for (int off = 1; off < 64; off <<= 1) v = fmax(v, __shfl_xor(v, off, 64));
  return v;
}

struct P1shm {
  __align__(16) __bf16 xs[CSEG][68];   // exp(x_t - m_t) bf16, 8.7 KB
  __align__(16) float m_arr[CSEG];
  __align__(16) float redmax[4];
  __align__(16) __bf16 P[2][64 * 68];  // col-major, stride 68, 17.4 KB
};
struct FACshm {
  __align__(16) _Float16 E[2][FCH][68];    // exp(x - m_row) f16, 4.4 KB
  __align__(16) _Float16 Eg[2][FCH][256];  // gathered, compute layout, 16 KB
  __align__(16) float m_fac[2][FCH];       // row maxes (stage-side)
  __align__(16) float mg[2][FCH];          // row maxes (compute-side copy)
};
union KU {
  P1shm p1;
  FACshm fac;
};

__global__ __launch_bounds__(256) void asg_k1(
    const float* __restrict__ inputs, const float* __restrict__ trans,
    const int* __restrict__ targets, const int* __restrict__ ilen,
    const int* __restrict__ tlenp, char* __restrict__ ws) {
  __shared__ KU u;
  const int tid = threadIdx.x, lane = tid & 63, wv = tid >> 6;
  const int bid = blockIdx.x;
  float* scales = (float*)(ws + OFF_SCALE);

  if (bid < 2 * B_) {
    // ================== FAC half-chains (exp domain, f64) ==================
    const bool isfwd = (bid < B_);
    const int b = bid & 63;
    const int len = ilen[b];
    const int tl = tlenp[b];
    const int TS = (len - 1) >> 1;
    double* vecout = (double*)(ws + (isfwd ? OFF_FWD : OFF_BWD)) + b * 256;
    float* Lout = (float*)(ws + (isfwd ? OFF_LF : OFF_LB));

    int tg0 = 0, tg1 = 0, tg2 = 0, tg3 = 0;
    if (wv == 0 || wv == 2) {
      int4 t4 = *(const int4*)(targets + b * S_ + lane * 4);
      tg0 = t4.x; tg1 = t4.y; tg2 = t4.z; tg3 = t4.w;
    }
    auto stage = [&](int c, int buf) {  // wave1: global -> E (f16), rowmax
#pragma unroll
      for (int i = 0; i < 4; ++i) {
        int f = lane + 64 * i;
        int r = f >> 4, c4 = f & 15;
        int t = c * FCH + r;
        if (t > T_ - 1) t = T_ - 1;
        float4 v = *(const float4*)(inputs + (size_t)t * (B_ * L_) + b * L_ +
                                    c4 * 4);
        float m = fmaxf(fmaxf(v.x, v.y), fmaxf(v.z, v.w));
#pragma unroll
        for (int off = 1; off < 16; off <<= 1)
          m = fmaxf(m, __shfl_xor(m, off, 64));
        f16x4 h;
        h[0] = (_Float16)__expf(v.x - m); h[1] = (_Float16)__expf(v.y - m);
        h[2] = (_Float16)__expf(v.z - m); h[3] = (_Float16)__expf(v.w - m);
        *(f16x4*)&u.fac.E[buf][r][c4 * 4] = h;
        if ((lane & 15) == 0) u.fac.m_fac[buf][r] = m;
      }
    };
    auto regather = [&](int c, int buf) {  // wave2: E -> Eg (compute layout)
#pragma unroll 4
      for (int r = 0; r < FCH; ++r) {
        f16x4 h;
        h[0] = u.fac.E[buf][r][tg0]; h[1] = u.fac.E[buf][r][tg1];
        h[2] = u.fac.E[buf][r][tg2]; h[3] = u.fac.E[buf][r][tg3];
        *(f16x4*)&u.fac.Eg[buf][r][lane * 4] = h;
      }
      if (lane < FCH) u.fac.mg[buf][lane] = u.fac.m_fac[buf][lane];
    };

    if (isfwd) {
      // ---------------- FORWARD: t = 1..TS ----------------
      double sw0 = 0, sw1 = 0, sw2 = 0, sw3 = 0;
      double mw0 = 0, mw1 = 0, mw2 = 0, mw3 = 0;
      if (wv == 0) {
        int tgm1 = (lane > 0) ? targets[b * S_ + lane * 4 - 1] : 0;
        sw0 = exp((double)trans[tg0 * 64 + tg0]);
        sw1 = exp((double)trans[tg1 * 64 + tg1]);
        sw2 = exp((double)trans[tg2 * 64 + tg2]);
        sw3 = exp((double)trans[tg3 * 64 + tg3]);
        mw0 = (lane == 0) ? 0.0 : exp((double)trans[tg0 * 64 + tgm1]);
        mw1 = exp((double)trans[tg1 * 64 + tg0]);
        mw2 = exp((double)trans[tg2 * 64 + tg1]);
        mw3 = exp((double)trans[tg3 * 64 + tg2]);
      }
      if (wv == 1) { stage(0, 0); stage(1, 1); }
      __syncthreads();
      if (wv == 2) regather(0, 0);
      __syncthreads();

      double d0 = 0.0, d1 = 0.0, d2 = 0.0, d3 = 0.0, shv = 0.0;
      float Lacc = 0.0f;
      const int addr_up = ((lane + 63) & 63) << 2;
      if (wv == 0) {
        if (lane == 0) d0 = (double)(float)u.fac.Eg[0][0][0];
        Lacc = u.fac.mg[0][0];
        __builtin_amdgcn_s_setprio(2);
      }
      for (int c = 0; 16 * c <= TS; ++c) {
        const int buf = c & 1;
        if (wv == 1) {
          if (16 * (c + 2) <= TS) stage(c + 2, buf);
        } else if (wv == 2) {
          if (16 * (c + 1) <= TS) regather(c + 1, buf ^ 1);
        } else if (wv == 0) {
          if (c) {  // exact power-of-2 rescale
            double dmax = wave_max64d(fmax(fmax(d0, d1), fmax(d2, d3)));
            long long lm = __double_as_longlong(dmax);
            int ex = (int)((lm >> 52) & 0x7FF);
            double M = __longlong_as_double((long long)(2046 - ex) << 52);
            d0 *= M; d1 *= M; d2 *= M; d3 *= M; shv *= M;
            Lacc += (float)(ex - 1023) * LN2;
          }
          const int r0 = (c == 0) ? 1 : 0;
          const int rmax = min(FCH, TS + 1 - 16 * c);
          f16x4 eH = *(const f16x4*)&u.fac.Eg[buf][r0][lane * 4];
          float mH = u.fac.mg[buf][r0];
          const int r1 = min(r0 + 1, FCH - 1);
          f16x4 pH = *(const f16x4*)&u.fac.Eg[buf][r1][lane * 4];
          float pM = u.fac.mg[buf][r1];
          for (int r = r0; r < rmax; ++r) {
            const int rn = min(r + 2, FCH - 1);
            f16x4 nH = *(const f16x4*)&u.fac.Eg[buf][rn][lane * 4];
            float nM = u.fac.mg[buf][rn];
            double nd3 = (double)(float)eH[3] * fma(mw3, d2, sw3 * d3);
            long long l3 = __double_as_longlong(nd3);
            int slo = __builtin_amdgcn_ds_bpermute(addr_up, (int)l3);
            int shi = __builtin_amdgcn_ds_bpermute(addr_up, (int)(l3 >> 32));
            double nd0 = (double)(float)eH[0] * fma(mw0, shv, sw0 * d0);
            double nd1 = (double)(float)eH[1] * fma(mw1, d0, sw1 * d1);
            double nd2 = (double)(float)eH[2] * fma(mw2, d1, sw2 * d2);
            d0 = nd0; d1 = nd1; d2 = nd2; d3 = nd3;
            shv = __longlong_as_double(((long long)shi << 32) |
                                       (unsigned int)slo);
            Lacc += mH;
            eH = pH; mH = pM; pH = nH; pM = nM;
          }
        }
        __syncthreads();
      }
      if (wv == 0) {
        __builtin_amdgcn_s_setprio(0);
        vecout[lane * 4 + 0] = d0; vecout[lane * 4 + 1] = d1;
        vecout[lane * 4 + 2] = d2; vecout[lane * 4 + 3] = d3;
        if (lane == 0) Lout[b] = Lacc;
      }
    } else {
      // ---------------- BACKWARD: t = len-1..TS+1 (transposed) ----------
      double sw0 = 0, sw1 = 0, sw2 = 0, sw3 = 0;
      double mv0 = 0, mv1 = 0, mv2 = 0, mv3 = 0;
      if (wv == 0) {
        int tg4 = (lane < 63) ? targets[b * S_ + lane * 4 + 4] : 0;
        sw0 = exp((double)trans[tg0 * 64 + tg0]);
        sw1 = exp((double)trans[tg1 * 64 + tg1]);
        sw2 = exp((double)trans[tg2 * 64 + tg2]);
        sw3 = exp((double)trans[tg3 * 64 + tg3]);
        mv0 = exp((double)trans[tg1 * 64 + tg0]);
        mv1 = exp((double)trans[tg2 * 64 + tg1]);
        mv2 = exp((double)trans[tg3 * 64 + tg2]);
        mv3 = (lane < 63) ? exp((double)trans[tg4 * 64 + tg3]) : 0.0;
      }
      const int cmax = (len - 1) >> 4;
      const int cmin = (TS + 1) >> 4;
      if (wv == 1) {
        stage(cmax, cmax & 1);
        if (cmax - 1 >= cmin) stage(cmax - 1, (cmax - 1) & 1);
      }
      __syncthreads();
      if (wv == 2) regather(cmax, cmax & 1);
      __syncthreads();

      const int idx = tl - 1;
      double b0 = 0, b1 = 0, b2 = 0, b3 = 0, g0cur = 0, shg = 0;
      float Lacc = 0.0f;
      const int addr_dn = ((lane + 1) & 63) << 2;
      if (wv == 0) {
        b0 = (lane * 4 + 0 == idx) ? 1.0 : 0.0;
        b1 = (lane * 4 + 1 == idx) ? 1.0 : 0.0;
        b2 = (lane * 4 + 2 == idx) ? 1.0 : 0.0;
        b3 = (lane * 4 + 3 == idx) ? 1.0 : 0.0;
        const int rh0 = (len - 1) & 15;
        float e0x = (float)u.fac.Eg[cmax & 1][rh0][lane * 4];
        g0cur = (double)e0x * b0;
        long long lg = __double_as_longlong(g0cur);
        int slo = __builtin_amdgcn_ds_bpermute(addr_dn, (int)lg);
        int shi = __builtin_amdgcn_ds_bpermute(addr_dn, (int)(lg >> 32));
        shg = __longlong_as_double(((long long)shi << 32) | (unsigned int)slo);
        __builtin_amdgcn_s_setprio(2);
      }
      for (int c = cmax; c >= cmin; --c) {
        const int buf = c & 1;
        if (wv == 1) {
          if (c - 2 >= cmin) stage(c - 2, buf);
        } else if (wv == 2) {
          if (c - 1 >= cmin) regather(c - 1, buf ^ 1);
        } else if (wv == 0) {
          if (c != cmax) {
            double dmax = wave_max64d(fmax(fmax(b0, b1), fmax(b2, b3)));
            long long lm = __double_as_longlong(dmax);
            int ex = (int)((lm >> 52) & 0x7FF);
            double M = __longlong_as_double((long long)(2046 - ex) << 52);
            b0 *= M; b1 *= M; b2 *= M; b3 *= M; g0cur *= M; shg *= M;
            Lacc += (float)(ex - 1023) * LN2;
          }
          const int rhi = (c == cmax) ? ((len - 1) & 15) : FCH - 1;
          const int rlo = max(0, (TS + 1) - 16 * c);
          f16x4 eH = *(const f16x4*)&u.fac.Eg[buf][rhi][lane * 4];
          float mH = u.fac.mg[buf][rhi];
          const int r1 = max(rhi - 1, rlo);
          f16x4 pH = *(const f16x4*)&u.fac.Eg[buf][r1][lane * 4];
          float pM = u.fac.mg[buf][r1];
          for (int r = rhi; r >= rlo; --r) {
            const int rn = max(r - 2, rlo);
            f16x4 nH = *(const f16x4*)&u.fac.Eg[buf][rn][lane * 4];
            float nM = u.fac.mg[buf][rn];
            double g1 = (double)(float)eH[1] * b1;
            double g2 = (double)(float)eH[2] * b2;
            double g3 = (double)(float)eH[3] * b3;
            double nb0 = fma(mv0, g1, sw0 * g0cur);
            double nb1 = fma(mv1, g2, sw1 * g1);
            double nb2 = fma(mv2, g3, sw2 * g2);
            double nb3 = fma(mv3, shg, sw3 * g3);
            double g0n = (double)(float)pH[0] * nb0;
            long long lg2 = __double_as_longlong(g0n);
            int slo2 = __builtin_amdgcn_ds_bpermute(addr_dn, (int)lg2);
            int shi2 = __builtin_amdgcn_ds_bpermute(addr_dn, (int)(lg2 >> 32));
            b0 = nb0; b1 = nb1; b2 = nb2; b3 = nb3;
            g0cur = g0n;
            shg = __longlong_as_double(((long long)shi2 << 32) |
                                       (unsigned int)slo2);
            Lacc += mH;
            eH = pH; mH = pM; pH = nH; pM = nM;
          }
        }
        __syncthreads();
      }
      if (wv == 0) {
        __builtin_amdgcn_s_setprio(0);
        vecout[lane * 4 + 0] = b0; vecout[lane * 4 + 1] = b1;
        vecout[lane * 4 + 2] = b2; vecout[lane * 4 + 3] = b3;
        if (lane == 0) Lout[b] = Lacc;
      }
    }
    return;
  }

  // ========================= FCC PHASE 1 (MFMA, 4-wave) =========================
  const int sid = bid - 2 * B_;
  const int b = sid >> 5, s = sid & 31;
  const int t0 = 1 + s * CSEG;
  const int len = ilen[b];
  int ke = min(CSEG, T_ - t0);
  ke = min(ke, len - t0);
  if (ke < 0) ke = 0;

  // stage xs = bf16(exp(x - rowmax)); rowmax in m_arr
#pragma unroll
  for (int i = 0; i < 4; ++i) {
    int f4 = tid + 256 * i;
    int r = f4 >> 4, c4 = f4 & 15;
    int t = t0 + r;
    if (t > T_ - 1) t = T_ - 1;
    float4 v = *(const float4*)(inputs + (size_t)t * (B_ * L_) + b * L_ + c4 * 4);
    float m = fmaxf(fmaxf(v.x, v.y), fmaxf(v.z, v.w));
#pragma unroll
    for (int off = 1; off < 16; off <<= 1)
      m = fmaxf(m, __shfl_xor(m, off, 64));
    bf16x4 h;
    h[0] = (__bf16)__expf(v.x - m); h[1] = (__bf16)__expf(v.y - m);
    h[2] = (__bf16)__expf(v.z - m); h[3] = (__bf16)__expf(v.w - m);
    *(bf16x4*)&u.p1.xs[r][c4 * 4] = h;
    if ((lane & 15) == 0) u.p1.m_arr[r] = m;
  }
  for (int i = tid; i < 64 * 68; i += 256) u.p1.P[0][i] = (__bf16)0.0f;
  __syncthreads();
  if (tid < 64) u.p1.P[0][tid * 68 + tid] = (__bf16)1.0f;

  const int ma = wv >> 1, nb = wv & 1;
  const int arow = 32 * ma + (lane & 31);
  const int hh = lane >> 5;
  const int coln = 32 * nb + (lane & 31);
  float Wf[4][8];
#pragma unroll
  for (int kc = 0; kc < 4; ++kc) {
    const float* tp = trans + arow * 64 + kc * 16 + hh * 8;
#pragma unroll
    for (int j = 0; j < 8; ++j) Wf[kc][j] = __expf(tp[j]);
  }

  float lsres = 0.0f;
  int cur = 0;
  for (int k = 0; k < ke; ++k) {
    __syncthreads();
    float scf = 1.0f;
    if ((k & 7) == 0 && k != 0) {
      float mm = fmaxf(fmaxf(u.p1.redmax[0], u.p1.redmax[1]),
                       fmaxf(u.p1.redmax[2], u.p1.redmax[3]));
      scf = __builtin_amdgcn_rcpf(mm);
      lsres += __logf(mm);
    }
    const float srow = (float)u.p1.xs[k][arow] * scf;
    bf16x8 A[4], Bf[4];
    const __bf16* Pc = u.p1.P[cur];
#pragma unroll
    for (int kc = 0; kc < 4; ++kc) {
#pragma unroll
      for (int j = 0; j < 8; ++j) A[kc][j] = (__bf16)(Wf[kc][j] * srow);
      const __bf16* p = Pc + coln * 68 + kc * 16 + hh * 8;
      bf16x4 lo = *(const bf16x4*)p;
      bf16x4 hi = *(const bf16x4*)(p + 4);
      Bf[kc] = __builtin_shufflevector(lo, hi, 0, 1, 2, 3, 4, 5, 6, 7);
    }
    f32x16 acc;
#pragma unroll
    for (int e = 0; e < 16; ++e) acc[e] = 0.0f;
    acc = __builtin_amdgcn_mfma_f32_32x32x16_bf16(A[0], Bf[0], acc, 0, 0, 0);
    acc = __builtin_amdgcn_mfma_f32_32x32x16_bf16(A[1], Bf[1], acc, 0, 0, 0);
    acc = __builtin_amdgcn_mfma_f32_32x32x16_bf16(A[2], Bf[2], acc, 0, 0, 0);
    acc = __builtin_amdgcn_mfma_f32_32x32x16_bf16(A[3], Bf[3], acc, 0, 0, 0);
    __bf16* Pn = u.p1.P[cur ^ 1];
#pragma unroll
    for (int q = 0; q < 4; ++q) {
      const int i0 = 32 * ma + 8 * q + 4 * hh;
      bf16x4 w;
      w[0] = (__bf16)acc[4 * q + 0]; w[1] = (__bf16)acc[4 * q + 1];
      w[2] = (__bf16)acc[4 * q + 2]; w[3] = (__bf16)acc[4 * q + 3];
      *(bf16x4*)(Pn + coln * 68 + i0) = w;
    }
    if ((k & 7) == 7) {
      float mx = acc[0];
#pragma unroll
      for (int e = 1; e < 16; ++e) mx = fmaxf(mx, acc[e]);
      mx = wave_max64(mx);
      if (lane == 0) u.p1.redmax[wv] = mx;
    }
    cur ^= 1;
  }
  __syncthreads();
  __bf16* G = ((__bf16*)ws) + (size_t)sid * 4096;
  const __bf16* Pf = u.p1.P[cur];
  for (int i = tid; i < 4096; i += 256) G[i] = Pf[(i >> 6) * 68 + (i & 63)];
  if (wv == 0) {
    float mt = (lane < ke) ? u.p1.m_arr[lane] : 0.0f;
    float msum = wave_sum64(mt);
    if (lane == 0) scales[sid] = msum + lsres;
  }
}

// K2: per-batch scan over 32 segment matrices (wave0 compute, wave1 stage).
__global__ __launch_bounds__(128) void asg_k2(const float* __restrict__ inputs,
                                              char* __restrict__ ws) {
  __shared__ __align__(16) float Gl[2][64][68];
  __shared__ __align__(16) float Eb[64];
  const int tid = threadIdx.x, lane = tid & 63, wv = tid >> 6;
  const int b = blockIdx.x;
  const __bf16* M = (const __bf16*)ws;
  const float* scales = (const float*)(ws + OFF_SCALE);
  float* full = (float*)(ws + OFF_FULL);

  auto stage = [&](int s, int buf) {
    const __bf16* g = M + ((size_t)(b * NSEG + s)) * 4096 + lane * 64;
#pragma unroll
    for (int q = 0; q < 8; ++q) {
      bf16x8 v = *(const bf16x8*)(g + q * 8);
      float4 f0{(float)v[0], (float)v[1], (float)v[2], (float)v[3]};
      float4 f1{(float)v[4], (float)v[5], (float)v[6], (float)v[7]};
      *(float4*)&Gl[buf][lane][q * 8] = f0;
      *(float4*)&Gl[buf][lane][q * 8 + 4] = f1;
    }
  };

  float Ev = 0.0f, ls = 0.0f;
  if (wv == 0) {
    float x0 = inputs[b * L_ + lane];
    float m0 = wave_max64(x0);
    Ev = __expf(x0 - m0);
    ls = m0;
    Eb[lane] = Ev;
  } else {
    stage(0, 0);
  }
  __syncthreads();
  for (int s = 0; s < NSEG; ++s) {
    if (wv == 1 && s + 1 < NSEG) stage(s + 1, (s + 1) & 1);
    if (wv == 0) {
      const int buf = s & 1;
      float ap0 = 0, ap1 = 0, ap2 = 0, ap3 = 0;
#pragma unroll
      for (int k4 = 0; k4 < 16; ++k4) {
        float4 e4 = *(const float4*)&Eb[k4 * 4];
        ap0 = fmaf(Gl[buf][4 * k4 + 0][lane], e4.x, ap0);
        ap1 = fmaf(Gl[buf][4 * k4 + 1][lane], e4.y, ap1);
        ap2 = fmaf(Gl[buf][4 * k4 + 2][lane], e4.z, ap2);
        ap3 = fmaf(Gl[buf][4 * k4 + 3][lane], e4.w, ap3);
      }
      float ap = (ap0 + ap1) + (ap2 + ap3);
      float mx = wave_max64(ap);
      float sc = __builtin_amdgcn_rcpf(mx);
      Ev = ap * sc;
      Eb[lane] = Ev;
      ls += __logf(mx) + scales[b * NSEG + s];
    }
    __syncthreads();
  }
  if (wv == 0) {
    float ssum = wave_sum64(Ev);
    if (lane == 0) full[b] = ls + __logf(ssum);
  }
}

// K3: per-batch dot(fwd,bwd) in f64, log-combine, mean over batches.
__global__ __launch_bounds__(256) void asg_k3(const char* __restrict__ ws,
                                              float* __restrict__ out) {
  __shared__ float diff[64];
  const int tid = threadIdx.x;
  const int b = tid >> 2, q = tid & 3;
  const double* fv = (const double*)(ws + OFF_FWD) + b * 256;
  const double* bv = (const double*)(ws + OFF_BWD) + b * 256;
  const float* full = (const float*)(ws + OFF_FULL);
  const float* Lf = (const float*)(ws + OFF_LF);
  const float* Lb = (const float*)(ws + OFF_LB);

  double s = 0.0;
  for (int j = q * 64; j < q * 64 + 64; ++j) s += fv[j] * bv[j];
  s += __shfl_xor(s, 1, 64);
  s += __shfl_xor(s, 2, 64);
  if (q == 0) {
    s = fmax(s, 1e-300);
    long long ls = __double_as_longlong(s);
    int ex = (int)((ls >> 52) & 0x7FF);
    double mant = __longlong_as_double((ls & 0xFFFFFFFFFFFFFLL) |
                                       (1023LL << 52));
    float alig = Lf[b] + Lb[b] + (float)(ex - 1023) * LN2 + __logf((float)mant);
    diff[b] = full[b] - alig;
  }
  __syncthreads();
  if (tid < 64) {
    float d = diff[tid];
    d = wave_sum64(d);
    if (tid == 0) out[0] = d * (1.0f / 64.0f);
  }
}

extern "C" void kernel_launch(void* const* d_in, const int* in_sizes, int n_in,
                              void* d_out, int out_size, void* d_ws,
                              size_t ws_size, hipStream_t stream) {
  const float* inputs = (const float*)d_in[0];
  const float* trans = (const float*)d_in[1];
  const int* targets = (const int*)d_in[2];
  const int* ilen = (const int*)d_in[3];
  const int* tlen = (const int*)d_in[4];
  char* ws = (char*)d_ws;
  float* out = (float*)d_out;

  hipLaunchKernelGGL(asg_k1, dim3(2 * B_ + NSEG * B_), dim3(256), 0, stream,
                     inputs, trans, targets, ilen, tlen, ws);
  hipLaunchKernelGGL(asg_k2, dim3(B_), dim3(128), 0, stream, inputs, ws);
  hipLaunchKernelGGL(asg_k3, dim3(1), dim3(256), 0, stream, ws, out);
}